// Round 1
// baseline (1429.739 us; speedup 1.0000x reference)
//
#include <hip/hip_runtime.h>

#define NN 8192
#define STEPS 128
#define CLAMP_V 0.999f
#define WPR 1024   // packed 4-bit words per row (8192/8)
#define NBLK 256
#define TPB 1024

#if __has_builtin(__builtin_amdgcn_sdot4)
#define DOT4(a, b, c) __builtin_amdgcn_sdot4((int)(a), (int)(b), (c), false)
#else
__device__ __forceinline__ int dot4_fb(int a, int b, int c) {
#pragma unroll
  for (int i = 0; i < 4; ++i)
    c += ((int)(signed char)(a >> (8 * i))) * ((int)(signed char)(b >> (8 * i)));
  return c;
}
#define DOT4(a, b, c) dot4_fb((int)(a), (int)(b), (c))
#endif

// =============== int4 quantization, dot4-friendly nibble order ===============
// word widx covers cols c0=8*widx .. c0+7. Nibble positions: {c0,c4,c1,c5,c2,c6,c3,c7}
// so lo=(w<<4)&0xF0F0F0F0 = {c0,c1,c2,c3}*16 and hi=w&0xF0F0F0F0 = {c4..c7}*16.
// scales[row] = rowmax/(7*16)  (folds the *16 of the nibble placement)
__global__ __launch_bounds__(256) void quant4_kernel(const float* __restrict__ K,
                                                     unsigned* __restrict__ Kq,
                                                     float* __restrict__ scales) {
  const int row = blockIdx.x;
  const int tid = threadIdx.x;
  const int wave = tid >> 6, lane = tid & 63;
  const size_t base = (size_t)row * NN;

  float4 va[4], vb[4];
  float mx = 0.f;
#pragma unroll
  for (int g = 0; g < 4; ++g) {
    const size_t o = base + (size_t)(g * 256 + tid) * 8;
    va[g] = *(const float4*)(K + o);
    vb[g] = *(const float4*)(K + o + 4);
    mx = fmaxf(mx, fmaxf(fmaxf(fabsf(va[g].x), fabsf(va[g].y)),
                         fmaxf(fabsf(va[g].z), fabsf(va[g].w))));
    mx = fmaxf(mx, fmaxf(fmaxf(fabsf(vb[g].x), fabsf(vb[g].y)),
                         fmaxf(fabsf(vb[g].z), fabsf(vb[g].w))));
  }
#pragma unroll
  for (int off = 32; off > 0; off >>= 1) mx = fmaxf(mx, __shfl_xor(mx, off));
  __shared__ float wm[4];
  if (lane == 0) wm[wave] = mx;
  __syncthreads();
  mx = fmaxf(fmaxf(wm[0], wm[1]), fmaxf(wm[2], wm[3]));

  const float inv = (mx > 0.f) ? 7.f / mx : 0.f;
  if (tid == 0) scales[row] = mx / 112.f;   // rowmax/(7*16)

#pragma unroll
  for (int g = 0; g < 4; ++g) {
    int qa[4], qb[4];
    const float a4[4] = {va[g].x, va[g].y, va[g].z, va[g].w};
    const float b4[4] = {vb[g].x, vb[g].y, vb[g].z, vb[g].w};
#pragma unroll
    for (int i = 0; i < 4; ++i) {
      qa[i] = max(-7, min(7, __float2int_rn(a4[i] * inv)));
      qb[i] = max(-7, min(7, __float2int_rn(b4[i] * inv)));
    }
    unsigned w = 0;
#pragma unroll
    for (int i = 0; i < 4; ++i) {
      w |= ((unsigned)(qa[i] & 0xF)) << (8 * i);        // c_i at nibble 2i
      w |= ((unsigned)(qb[i] & 0xF)) << (8 * i + 4);    // c_{4+i} at nibble 2i+1
    }
    Kq[(size_t)row * WPR + g * 256 + tid] = w;
  }
}

// =============== prep: quantize initial z (unbounded) with dynamic scale ===============
// Also zeroes the grid-barrier state (must happen each graph replay, before persist).
__global__ __launch_bounds__(256) void prep_kernel(const float* __restrict__ z,
                                                   signed char* __restrict__ zre,
                                                   signed char* __restrict__ zim,
                                                   float* __restrict__ scz,
                                                   unsigned* __restrict__ bar) {
  const int tid = threadIdx.x;
  const int wave = tid >> 6, lane = tid & 63;
  float4 buf[16];
  float mx = 0.f;
#pragma unroll
  for (int j = 0; j < 16; ++j) {
    buf[j] = *(const float4*)(z + tid * 64 + j * 4);
    mx = fmaxf(mx, fmaxf(fmaxf(fabsf(buf[j].x), fabsf(buf[j].y)),
                         fmaxf(fabsf(buf[j].z), fabsf(buf[j].w))));
  }
#pragma unroll
  for (int off = 32; off > 0; off >>= 1) mx = fmaxf(mx, __shfl_xor(mx, off));
  __shared__ float wm[4];
  if (lane == 0) wm[wave] = mx;
  __syncthreads();
  mx = fmaxf(fmaxf(wm[0], wm[1]), fmaxf(wm[2], wm[3]));
  const float q = (mx > 0.f) ? 127.f / mx : 0.f;
  if (tid == 0) {
    scz[0] = mx / 127.f;
    __hip_atomic_store(&bar[0], 0u, __ATOMIC_RELAXED, __HIP_MEMORY_SCOPE_AGENT);
    __hip_atomic_store(&bar[1], 0u, __ATOMIC_RELAXED, __HIP_MEMORY_SCOPE_AGENT);
  }
#pragma unroll
  for (int j = 0; j < 16; ++j) {
    const int i0 = tid * 32 + 2 * j;
    zre[i0]     = (signed char)max(-127, min(127, __float2int_rn(buf[j].x * q)));
    zim[i0]     = (signed char)max(-127, min(127, __float2int_rn(buf[j].y * q)));
    zre[i0 + 1] = (signed char)max(-127, min(127, __float2int_rn(buf[j].z * q)));
    zim[i0 + 1] = (signed char)max(-127, min(127, __float2int_rn(buf[j].w * q)));
  }
}

// =============== persistent kernel: all 128 steps, K resident in VGPRs ===============
// 256 blocks x 1024 threads (16 waves). Block owns 32 rows; wave owns 2 rows.
// Per lane: 16 packed int4-words per row (4x uint4, 32 VGPRs total) held across all steps.
// Cross-block state per step = int8 z-planes only, moved via agent-scope (coherent) atomics.
// Co-residency: __launch_bounds__(1024,4) => VGPR<=128 => >=1 block/CU; grid = 256 = #CUs,
// capacity >= 2x grid, so all blocks are resident regardless of placement -> barrier is safe.

#define KW_ACC(KWRD, ZRL, ZRH, ZIL, ZIH, SR, SI)               \
  {                                                            \
    const unsigned lo_ = ((KWRD) << 4) & 0xF0F0F0F0u;          \
    const unsigned hi_ = (KWRD) & 0xF0F0F0F0u;                 \
    SR = DOT4(lo_, ZRL, SR); SR = DOT4(hi_, ZRH, SR);          \
    SI = DOT4(lo_, ZIL, SI); SI = DOT4(hi_, ZIH, SI);          \
  }

__global__ __launch_bounds__(TPB, 4)
void persist_kernel(const unsigned* __restrict__ Kq, const float* __restrict__ scales,
                    const float* __restrict__ z_in,
                    signed char* __restrict__ q_re0, signed char* __restrict__ q_im0,
                    signed char* __restrict__ q_re1, signed char* __restrict__ q_im1,
                    const float* __restrict__ scz_p,
                    const float* __restrict__ omega_p, const float* __restrict__ dt_p,
                    float* __restrict__ out, unsigned* __restrict__ bar) {
  const int tid = threadIdx.x;
  const int wave = tid >> 6, lane = tid & 63;
  const int rowA = blockIdx.x * 32 + wave * 2;
  const int rowB = rowA + 1;

  __shared__ unsigned long long lds_re[1024];   // 8 KiB: re plane (8 int8 per u64)
  __shared__ unsigned long long lds_im[1024];   // 8 KiB: im plane

  // ---- one-time: K rows into registers (2 rows x 4 uint4 per lane) ----
  uint4 kA[4], kB[4];
  {
    const unsigned* kpA = Kq + (size_t)rowA * WPR + lane * 4;
    const unsigned* kpB = Kq + (size_t)rowB * WPR + lane * 4;
#pragma unroll
    for (int it = 0; it < 4; ++it) {
      kA[it] = *(const uint4*)(kpA + it * 256);
      kB[it] = *(const uint4*)(kpB + it * 256);
    }
  }

  // ---- one-time: f32 z state for owned rows (kept in registers all 128 steps) ----
  float zrA = z_in[2 * rowA], ziA = z_in[2 * rowA + 1];
  float zrB = z_in[2 * rowB], ziB = z_in[2 * rowB + 1];
  const float scA = scales[rowA], scB = scales[rowB];
  const float omega = *omega_p, dt = *dt_p;
  const float inv2n = 1.0f / (2.0f * (float)NN);
  float sz = *scz_p;   // step-0 z scale; becomes 1/127 afterwards

  for (int s = 0; s < STEPS; ++s) {
    const signed char* qre = (s & 1) ? q_re1 : q_re0;
    const signed char* qim = (s & 1) ? q_im1 : q_im0;

    // stage z planes to LDS with agent-coherent loads (bypass stale L1/L2)
    lds_re[tid] = __hip_atomic_load((const unsigned long long*)qre + tid,
                                    __ATOMIC_RELAXED, __HIP_MEMORY_SCOPE_AGENT);
    lds_im[tid] = __hip_atomic_load((const unsigned long long*)qim + tid,
                                    __ATOMIC_RELAXED, __HIP_MEMORY_SCOPE_AGENT);
    __syncthreads();

    int srA = 0, siA = 0, srB = 0, siB = 0;
#pragma unroll
    for (int it = 0; it < 4; ++it) {
      const int w0 = it * 256 + lane * 4;           // 4 consecutive words
      const unsigned long long* lr = lds_re + w0;   // byte off 8*w0, 32B-aligned
      const unsigned long long* li = lds_im + w0;
      const uint4 zr01 = *(const uint4*)lr;         // re bytes of words w0,w0+1
      const uint4 zr23 = *(const uint4*)(lr + 2);   // re bytes of words w0+2,w0+3
      const uint4 zi01 = *(const uint4*)li;
      const uint4 zi23 = *(const uint4*)(li + 2);
      KW_ACC(kA[it].x, zr01.x, zr01.y, zi01.x, zi01.y, srA, siA)
      KW_ACC(kA[it].y, zr01.z, zr01.w, zi01.z, zi01.w, srA, siA)
      KW_ACC(kA[it].z, zr23.x, zr23.y, zi23.x, zi23.y, srA, siA)
      KW_ACC(kA[it].w, zr23.z, zr23.w, zi23.z, zi23.w, srA, siA)
      KW_ACC(kB[it].x, zr01.x, zr01.y, zi01.x, zi01.y, srB, siB)
      KW_ACC(kB[it].y, zr01.z, zr01.w, zi01.z, zi01.w, srB, siB)
      KW_ACC(kB[it].z, zr23.x, zr23.y, zi23.x, zi23.y, srB, siB)
      KW_ACC(kB[it].w, zr23.z, zr23.w, zi23.z, zi23.w, srB, siB)
    }

    // exact integer wave reduction
#pragma unroll
    for (int off = 32; off > 0; off >>= 1) {
      srA += __shfl_xor(srA, off);
      siA += __shfl_xor(siA, off);
      srB += __shfl_xor(srB, off);
      siB += __shfl_xor(siB, off);
    }

    // z update (redundant across lanes; identical math to previous kernel)
    const float facA = scA * sz, facB = scB * sz;
    const float WrA = (float)srA * facA, WiA = (float)siA * facA;
    const float WrB = (float)srB * facB, WiB = (float)siB * facB;

    float nrA, niA, nrB, niB;
    {
      const float z2r = zrA * zrA - ziA * ziA;
      const float z2i = 2.0f * zrA * ziA;
      const float t1r = -inv2n * (WrA * z2r + WiA * z2i);
      const float t1i = -inv2n * (WrA * z2i - WiA * z2r);
      nrA = zrA + dt * (t1r + omega * zrA + inv2n * WrA);
      niA = ziA + dt * (t1i + omega * ziA + inv2n * WiA);
      const float a = sqrtf(nrA * nrA + niA * niA);
      if (a >= CLAMP_V) { nrA = nrA / a * CLAMP_V; niA = niA / a * CLAMP_V; }
    }
    {
      const float z2r = zrB * zrB - ziB * ziB;
      const float z2i = 2.0f * zrB * ziB;
      const float t1r = -inv2n * (WrB * z2r + WiB * z2i);
      const float t1i = -inv2n * (WrB * z2i - WiB * z2r);
      nrB = zrB + dt * (t1r + omega * zrB + inv2n * WrB);
      niB = ziB + dt * (t1i + omega * ziB + inv2n * WiB);
      const float a = sqrtf(nrB * nrB + niB * niB);
      if (a >= CLAMP_V) { nrB = nrB / a * CLAMP_V; niB = niB / a * CLAMP_V; }
    }
    zrA = nrA; ziA = niA; zrB = nrB; ziB = niB;
    if (s == 0) sz = 1.0f / 127.f;

    if (s == STEPS - 1) {
      if (lane == 0) {
        float frA = nrA, fiA = niA, frB = nrB, fiB = niB;
        const float n2 = sqrtf(frA * frA + fiA * fiA);
        if (n2 >= CLAMP_V) { frA = frA / n2 * CLAMP_V; fiA = fiA / n2 * CLAMP_V; }
        const float n3 = sqrtf(frB * frB + fiB * fiB);
        if (n3 >= CLAMP_V) { frB = frB / n3 * CLAMP_V; fiB = fiB / n3 * CLAMP_V; }
        float4 o; o.x = frA; o.y = fiA; o.z = frB; o.w = fiB;
        *(float4*)(out + 2 * rowA) = o;   // rows A,B contiguous, 16B-aligned
      }
    } else {
      if (lane == 0) {
        signed char* qre_n = (s & 1) ? q_re0 : q_re1;
        signed char* qim_n = (s & 1) ? q_im0 : q_im1;
        const int ar = __float2int_rn(nrA * 127.f), ai = __float2int_rn(niA * 127.f);
        const int br = __float2int_rn(nrB * 127.f), bi = __float2int_rn(niB * 127.f);
        const unsigned short pr = (unsigned short)((ar & 0xFF) | ((br & 0xFF) << 8));
        const unsigned short pi = (unsigned short)((ai & 0xFF) | ((bi & 0xFF) << 8));
        __hip_atomic_store((unsigned short*)(qre_n + rowA), pr,
                           __ATOMIC_RELAXED, __HIP_MEMORY_SCOPE_AGENT);
        __hip_atomic_store((unsigned short*)(qim_n + rowA), pi,
                           __ATOMIC_RELAXED, __HIP_MEMORY_SCOPE_AGENT);
      }
      // ---- grid barrier (software, agent scope) ----
      __syncthreads();   // drains all waves' vmem stores (compiler emits vmcnt(0))
      if (tid == 0) {
        const unsigned target = (unsigned)(s + 1);
        const unsigned prev = __hip_atomic_fetch_add(&bar[0], 1u, __ATOMIC_ACQ_REL,
                                                     __HIP_MEMORY_SCOPE_AGENT);
        if (prev == (unsigned)(NBLK - 1)) {
          __hip_atomic_store(&bar[0], 0u, __ATOMIC_RELAXED, __HIP_MEMORY_SCOPE_AGENT);
          __hip_atomic_store(&bar[1], target, __ATOMIC_RELEASE, __HIP_MEMORY_SCOPE_AGENT);
        } else {
          while (__hip_atomic_load(&bar[1], __ATOMIC_RELAXED,
                                   __HIP_MEMORY_SCOPE_AGENT) < target)
            __builtin_amdgcn_s_sleep(1);
        }
      }
      __syncthreads();
    }
  }
}

// =============== f32 fallback (no workspace) ===============
__global__ __launch_bounds__(256, 2)
void step_f32(const float* __restrict__ K,
              const float* __restrict__ z_old, float* __restrict__ z_new,
              const float* __restrict__ omega_p, const float* __restrict__ dt_p) {
  const int tid = threadIdx.x;
  const int wave = tid >> 6, lane = tid & 63;
  const int row0 = blockIdx.x * 8;
  __shared__ float red[4][16];
  float ar[8] = {0, 0, 0, 0, 0, 0, 0, 0};
  float ai[8] = {0, 0, 0, 0, 0, 0, 0, 0};
  const int cbase = wave * 2048 + lane * 8;
#pragma unroll
  for (int it = 0; it < 4; ++it) {
    const int c = cbase + it * 512;
    const float4 zA = *(const float4*)(z_old + 2 * c + 0);
    const float4 zB = *(const float4*)(z_old + 2 * c + 4);
    const float4 zC = *(const float4*)(z_old + 2 * c + 8);
    const float4 zD = *(const float4*)(z_old + 2 * c + 12);
#pragma unroll
    for (int r = 0; r < 8; ++r) {
      const float* kp = K + (size_t)(row0 + r) * NN + c;
      const float4 ka = *(const float4*)kp;
      const float4 kb = *(const float4*)(kp + 4);
      float sr = ar[r], si = ai[r];
      sr = fmaf(ka.x, zA.x, sr); si = fmaf(ka.x, zA.y, si);
      sr = fmaf(ka.y, zA.z, sr); si = fmaf(ka.y, zA.w, si);
      sr = fmaf(ka.z, zB.x, sr); si = fmaf(ka.z, zB.y, si);
      sr = fmaf(ka.w, zB.z, sr); si = fmaf(ka.w, zB.w, si);
      sr = fmaf(kb.x, zC.x, sr); si = fmaf(kb.x, zC.y, si);
      sr = fmaf(kb.y, zC.z, sr); si = fmaf(kb.y, zC.w, si);
      sr = fmaf(kb.z, zD.x, sr); si = fmaf(kb.z, zD.y, si);
      sr = fmaf(kb.w, zD.z, sr); si = fmaf(kb.w, zD.w, si);
      ar[r] = sr; ai[r] = si;
    }
  }
#pragma unroll
  for (int off = 32; off > 0; off >>= 1) {
#pragma unroll
    for (int r = 0; r < 8; ++r) {
      ar[r] += __shfl_xor(ar[r], off);
      ai[r] += __shfl_xor(ai[r], off);
    }
  }
  if (lane == 0) {
#pragma unroll
    for (int r = 0; r < 8; ++r) {
      red[wave][2 * r + 0] = ar[r];
      red[wave][2 * r + 1] = ai[r];
    }
  }
  __syncthreads();
  if (tid < 8) {
    const float Wr = red[0][2 * tid] + red[1][2 * tid] + red[2][2 * tid] + red[3][2 * tid];
    const float Wi = red[0][2 * tid + 1] + red[1][2 * tid + 1] +
                     red[2][2 * tid + 1] + red[3][2 * tid + 1];
    const int row = row0 + tid;
    const float omega = *omega_p;
    const float dt = *dt_p;
    const float inv2n = 1.0f / (2.0f * (float)NN);
    const float zr = z_old[2 * row];
    const float zi = z_old[2 * row + 1];
    const float z2r = zr * zr - zi * zi;
    const float z2i = 2.0f * zr * zi;
    const float t1r = -inv2n * (Wr * z2r + Wi * z2i);
    const float t1i = -inv2n * (Wr * z2i - Wi * z2r);
    float nr = zr + dt * (t1r + omega * zr + inv2n * Wr);
    float ni = zi + dt * (t1i + omega * zi + inv2n * Wi);
    const float a = sqrtf(nr * nr + ni * ni);
    if (a >= CLAMP_V) { nr = nr / a * CLAMP_V; ni = ni / a * CLAMP_V; }
    z_new[2 * row] = nr;
    z_new[2 * row + 1] = ni;
  }
}

__global__ __launch_bounds__(256) void finalize_kernel(const float* __restrict__ z,
                                                       float* __restrict__ out) {
  int i = blockIdx.x * blockDim.x + threadIdx.x;
  if (i < NN) {
    float x = z[2 * i], y = z[2 * i + 1];
    float n = sqrtf(x * x + y * y);
    if (n >= CLAMP_V) { x = x / n * CLAMP_V; y = y / n * CLAMP_V; }
    out[2 * i] = x;
    out[2 * i + 1] = y;
  }
}

extern "C" void kernel_launch(void* const* d_in, const int* in_sizes, int n_in,
                              void* d_out, int out_size, void* d_ws, size_t ws_size,
                              hipStream_t stream) {
  const float* z_in = (const float*)d_in[0];      // [8192,2] f32
  const float* K = (const float*)d_in[1];         // [8192,8192] f32
  const float* omega_p = (const float*)d_in[2];   // scalar f32
  const float* dt_p = (const float*)d_in[3];      // scalar f32
  float* out = (float*)d_out;

  char* ws = (char*)d_ws;
  const size_t kq_bytes = (size_t)NN * WPR * sizeof(unsigned);  // 32 MiB
  const size_t sc_bytes = (size_t)NN * sizeof(float);           // 32 KiB
  const size_t plane = (size_t)NN;                              // 8 KiB per i8 plane
  const size_t need = kq_bytes + sc_bytes + 4 * plane + 256;
  const bool use_q = ws_size >= need;

  if (use_q) {
    size_t off = 0;
    unsigned* Kq = (unsigned*)(ws + off); off += kq_bytes;
    float* scales = (float*)(ws + off); off += sc_bytes;
    signed char* q_re0 = (signed char*)(ws + off); off += plane;
    signed char* q_im0 = (signed char*)(ws + off); off += plane;
    signed char* q_re1 = (signed char*)(ws + off); off += plane;
    signed char* q_im1 = (signed char*)(ws + off); off += plane;
    float* scz = (float*)(ws + off); off += 16;
    unsigned* bar = (unsigned*)(ws + off);

    quant4_kernel<<<NN, 256, 0, stream>>>(K, Kq, scales);
    prep_kernel<<<1, 256, 0, stream>>>(z_in, q_re0, q_im0, scz, bar);
    persist_kernel<<<NBLK, TPB, 0, stream>>>(Kq, scales, z_in,
                                             q_re0, q_im0, q_re1, q_im1,
                                             scz, omega_p, dt_p, out, bar);
  } else {
    float* zb0 = (float*)ws;
    float* zb1 = zb0 + NN * 2;
    const float* src = z_in;
    for (int s = 0; s < STEPS; ++s) {
      float* dst = (s & 1) ? zb1 : zb0;
      step_f32<<<NN / 8, 256, 0, stream>>>(K, src, dst, omega_p, dt_p);
      src = dst;
    }
    finalize_kernel<<<(NN + 255) / 256, 256, 0, stream>>>(src, out);
  }
}

// Round 2
// 1224.783 us; speedup vs baseline: 1.1673x; 1.1673x over previous
//
#include <hip/hip_runtime.h>

#define NN 8192
#define STEPS 128
#define CLAMP_V 0.999f
#define WPR 1024   // packed 4-bit words per row (8192/8)
#define NBLK 256
#define TPB 1024

#if __has_builtin(__builtin_amdgcn_sdot4)
#define DOT4(a, b, c) __builtin_amdgcn_sdot4((int)(a), (int)(b), (c), false)
#else
__device__ __forceinline__ int dot4_fb(int a, int b, int c) {
#pragma unroll
  for (int i = 0; i < 4; ++i)
    c += ((int)(signed char)(a >> (8 * i))) * ((int)(signed char)(b >> (8 * i)));
  return c;
}
#define DOT4(a, b, c) dot4_fb((int)(a), (int)(b), (c))
#endif

// =============== int4 quantization, dot4-friendly nibble order ===============
// word widx covers cols c0=8*widx .. c0+7. Nibble positions: {c0,c4,c1,c5,c2,c6,c3,c7}
// so lo=(w<<4)&0xF0F0F0F0 = {c0,c1,c2,c3}*16 and hi=w&0xF0F0F0F0 = {c4..c7}*16.
// scales[row] = rowmax/(7*16)  (folds the *16 of the nibble placement)
__global__ __launch_bounds__(256) void quant4_kernel(const float* __restrict__ K,
                                                     unsigned* __restrict__ Kq,
                                                     float* __restrict__ scales) {
  const int row = blockIdx.x;
  const int tid = threadIdx.x;
  const int wave = tid >> 6, lane = tid & 63;
  const size_t base = (size_t)row * NN;

  float4 va[4], vb[4];
  float mx = 0.f;
#pragma unroll
  for (int g = 0; g < 4; ++g) {
    const size_t o = base + (size_t)(g * 256 + tid) * 8;
    va[g] = *(const float4*)(K + o);
    vb[g] = *(const float4*)(K + o + 4);
    mx = fmaxf(mx, fmaxf(fmaxf(fabsf(va[g].x), fabsf(va[g].y)),
                         fmaxf(fabsf(va[g].z), fabsf(va[g].w))));
    mx = fmaxf(mx, fmaxf(fmaxf(fabsf(vb[g].x), fabsf(vb[g].y)),
                         fmaxf(fabsf(vb[g].z), fabsf(vb[g].w))));
  }
#pragma unroll
  for (int off = 32; off > 0; off >>= 1) mx = fmaxf(mx, __shfl_xor(mx, off));
  __shared__ float wm[4];
  if (lane == 0) wm[wave] = mx;
  __syncthreads();
  mx = fmaxf(fmaxf(wm[0], wm[1]), fmaxf(wm[2], wm[3]));

  const float inv = (mx > 0.f) ? 7.f / mx : 0.f;
  if (tid == 0) scales[row] = mx / 112.f;   // rowmax/(7*16)

#pragma unroll
  for (int g = 0; g < 4; ++g) {
    int qa[4], qb[4];
    const float a4[4] = {va[g].x, va[g].y, va[g].z, va[g].w};
    const float b4[4] = {vb[g].x, vb[g].y, vb[g].z, vb[g].w};
#pragma unroll
    for (int i = 0; i < 4; ++i) {
      qa[i] = max(-7, min(7, __float2int_rn(a4[i] * inv)));
      qb[i] = max(-7, min(7, __float2int_rn(b4[i] * inv)));
    }
    unsigned w = 0;
#pragma unroll
    for (int i = 0; i < 4; ++i) {
      w |= ((unsigned)(qa[i] & 0xF)) << (8 * i);        // c_i at nibble 2i
      w |= ((unsigned)(qb[i] & 0xF)) << (8 * i + 4);    // c_{4+i} at nibble 2i+1
    }
    Kq[(size_t)row * WPR + g * 256 + tid] = w;
  }
}

// =============== prep: quantize initial z; zero the barrier slots ===============
__global__ __launch_bounds__(256) void prep_kernel(const float* __restrict__ z,
                                                   signed char* __restrict__ zre,
                                                   signed char* __restrict__ zim,
                                                   float* __restrict__ scz,
                                                   unsigned* __restrict__ arr) {
  const int tid = threadIdx.x;
  const int wave = tid >> 6, lane = tid & 63;
  float4 buf[16];
  float mx = 0.f;
#pragma unroll
  for (int j = 0; j < 16; ++j) {
    buf[j] = *(const float4*)(z + tid * 64 + j * 4);
    mx = fmaxf(mx, fmaxf(fmaxf(fabsf(buf[j].x), fabsf(buf[j].y)),
                         fmaxf(fabsf(buf[j].z), fabsf(buf[j].w))));
  }
#pragma unroll
  for (int off = 32; off > 0; off >>= 1) mx = fmaxf(mx, __shfl_xor(mx, off));
  __shared__ float wm[4];
  if (lane == 0) wm[wave] = mx;
  __syncthreads();
  mx = fmaxf(fmaxf(wm[0], wm[1]), fmaxf(wm[2], wm[3]));
  const float q = (mx > 0.f) ? 127.f / mx : 0.f;
  if (tid == 0) scz[0] = mx / 127.f;
  // zero barrier slots every launch (graph replay safe)
  __hip_atomic_store(&arr[tid], 0u, __ATOMIC_RELAXED, __HIP_MEMORY_SCOPE_AGENT);
#pragma unroll
  for (int j = 0; j < 16; ++j) {
    const int i0 = tid * 32 + 2 * j;
    zre[i0]     = (signed char)max(-127, min(127, __float2int_rn(buf[j].x * q)));
    zim[i0]     = (signed char)max(-127, min(127, __float2int_rn(buf[j].y * q)));
    zre[i0 + 1] = (signed char)max(-127, min(127, __float2int_rn(buf[j].z * q)));
    zim[i0 + 1] = (signed char)max(-127, min(127, __float2int_rn(buf[j].w * q)));
  }
}

// =============== persistent kernel: all 128 steps, K resident in VGPRs ===============
// 256 blocks x 1024 threads (16 waves). Block owns 32 rows; wave owns 2 rows (full width).
// K register layout: lane l owns word seg*64+l (seg=0..15) per row, PRE-UNPACKED into
// kLo/kHi (64 VGPRs). Matching z LDS layout: lane l reads u64 at word seg*64+l ->
// ds_read_b64 with 8B lane stride = 2 lanes/bank = conflict-free.
// Update phase: wave 0 only; lane r (<32) owns row row0+r, keeps z f32 state in regs.
// Grid barrier: distributed slots arr[256]; release-store own slot, poll all 256 via
// 4 coalesced agent loads/lane + __all. No atomic RMW anywhere.
__global__ __launch_bounds__(TPB, 4)
void persist_kernel(const unsigned* __restrict__ Kq, const float* __restrict__ scales,
                    const float* __restrict__ z_in,
                    signed char* __restrict__ q_re0, signed char* __restrict__ q_im0,
                    signed char* __restrict__ q_re1, signed char* __restrict__ q_im1,
                    const float* __restrict__ scz_p,
                    const float* __restrict__ omega_p, const float* __restrict__ dt_p,
                    float* __restrict__ out, unsigned* __restrict__ arr) {
  const int tid = threadIdx.x;
  const int wave = tid >> 6, lane = tid & 63;
  const int row0 = blockIdx.x * 32;
  const int rowA = row0 + wave * 2;
  const int rowB = rowA + 1;

  __shared__ unsigned long long lds_re[1024];   // 8 KiB re plane
  __shared__ unsigned long long lds_im[1024];   // 8 KiB im plane
  __shared__ int red[16][4];                    // per-wave {srA,siA,srB,siB}

  // ---- one-time: K rows into registers, pre-unpacked (word index = seg*64+lane) ----
  unsigned kLoA[16], kHiA[16], kLoB[16], kHiB[16];
  {
    const unsigned* kpA = Kq + (size_t)rowA * WPR + lane;
    const unsigned* kpB = Kq + (size_t)rowB * WPR + lane;
#pragma unroll
    for (int seg = 0; seg < 16; ++seg) {
      const unsigned wA = kpA[seg * 64];
      const unsigned wB = kpB[seg * 64];
      kLoA[seg] = (wA << 4) & 0xF0F0F0F0u;
      kHiA[seg] = wA & 0xF0F0F0F0u;
      kLoB[seg] = (wB << 4) & 0xF0F0F0F0u;
      kHiB[seg] = wB & 0xF0F0F0F0u;
    }
  }

  // ---- one-time: wave 0 lane r owns row row0+r: f32 z state + scale in regs ----
  float zr_s = 0.f, zi_s = 0.f, myScale = 0.f;
  if (wave == 0 && lane < 32) {
    const int row = row0 + lane;
    zr_s = z_in[2 * row];
    zi_s = z_in[2 * row + 1];
    myScale = scales[row];
  }
  const float omega = *omega_p, dt = *dt_p;
  const float inv2n = 1.0f / (2.0f * (float)NN);
  const float sz0 = *scz_p;

  for (int s = 0; s < STEPS; ++s) {
    const unsigned long long* qre =
        (const unsigned long long*)((s & 1) ? q_re1 : q_re0);
    const unsigned long long* qim =
        (const unsigned long long*)((s & 1) ? q_im1 : q_im0);

    // stage z planes to LDS (agent-coherent loads -> LLC, never stale)
    lds_re[tid] = __hip_atomic_load(qre + tid, __ATOMIC_RELAXED, __HIP_MEMORY_SCOPE_AGENT);
    lds_im[tid] = __hip_atomic_load(qim + tid, __ATOMIC_RELAXED, __HIP_MEMORY_SCOPE_AGENT);
    __syncthreads();

    int srA = 0, siA = 0, srB = 0, siB = 0;
#pragma unroll
    for (int seg = 0; seg < 16; ++seg) {
      const unsigned long long zr = lds_re[seg * 64 + lane];  // 8B stride: conflict-free
      const unsigned long long zi = lds_im[seg * 64 + lane];
      const unsigned zrl = (unsigned)zr, zrh = (unsigned)(zr >> 32);
      const unsigned zil = (unsigned)zi, zih = (unsigned)(zi >> 32);
      srA = DOT4(kLoA[seg], zrl, srA); srA = DOT4(kHiA[seg], zrh, srA);
      siA = DOT4(kLoA[seg], zil, siA); siA = DOT4(kHiA[seg], zih, siA);
      srB = DOT4(kLoB[seg], zrl, srB); srB = DOT4(kHiB[seg], zrh, srB);
      siB = DOT4(kLoB[seg], zil, siB); siB = DOT4(kHiB[seg], zih, siB);
    }

    // exact integer wave butterfly
#pragma unroll
    for (int off = 32; off > 0; off >>= 1) {
      srA += __shfl_xor(srA, off); siA += __shfl_xor(siA, off);
      srB += __shfl_xor(srB, off); siB += __shfl_xor(siB, off);
    }
    if (lane == 0) {
      red[wave][0] = srA; red[wave][1] = siA;
      red[wave][2] = srB; red[wave][3] = siB;
    }
    __syncthreads();

    if (wave == 0) {
      if (lane < 32) {
        const int w = lane >> 1, idx = lane & 1;
        const float sz = (s == 0) ? sz0 : (1.f / 127.f);
        const float fac = myScale * sz;
        const float Wr = (float)red[w][2 * idx] * fac;
        const float Wi = (float)red[w][2 * idx + 1] * fac;
        const float z2r = zr_s * zr_s - zi_s * zi_s;
        const float z2i = 2.0f * zr_s * zi_s;
        const float t1r = -inv2n * (Wr * z2r + Wi * z2i);
        const float t1i = -inv2n * (Wr * z2i - Wi * z2r);
        float nr = zr_s + dt * (t1r + omega * zr_s + inv2n * Wr);
        float ni = zi_s + dt * (t1i + omega * zi_s + inv2n * Wi);
        const float a = sqrtf(nr * nr + ni * ni);
        if (a >= CLAMP_V) { nr = nr / a * CLAMP_V; ni = ni / a * CLAMP_V; }
        zr_s = nr; zi_s = ni;
        if (s == STEPS - 1) {
          float fr = nr, fi = ni;
          const float n2 = sqrtf(fr * fr + fi * fi);
          if (n2 >= CLAMP_V) { fr = fr / n2 * CLAMP_V; fi = fi / n2 * CLAMP_V; }
          float2 o; o.x = fr; o.y = fi;
          *(float2*)(out + 2 * (row0 + lane)) = o;
        } else {
          signed char* qre_n = (s & 1) ? q_re0 : q_re1;
          signed char* qim_n = (s & 1) ? q_im0 : q_im1;
          const signed char pr = (signed char)__float2int_rn(nr * 127.f);
          const signed char pi = (signed char)__float2int_rn(ni * 127.f);
          __hip_atomic_store(qre_n + row0 + lane, pr,
                             __ATOMIC_RELAXED, __HIP_MEMORY_SCOPE_AGENT);
          __hip_atomic_store(qim_n + row0 + lane, pi,
                             __ATOMIC_RELAXED, __HIP_MEMORY_SCOPE_AGENT);
        }
      }
      if (s < STEPS - 1) {
        const unsigned tgt = (unsigned)(s + 1);
        if (lane == 0) {
          // release: wave's plane-stores drained (vmcnt) + visible before flag
          __hip_atomic_store(&arr[blockIdx.x], tgt,
                             __ATOMIC_RELEASE, __HIP_MEMORY_SCOPE_AGENT);
        }
        // all 64 lanes poll all 256 slots: 4 coalesced agent loads + __all
        for (;;) {
          const unsigned a0 = __hip_atomic_load(&arr[lane], __ATOMIC_RELAXED,
                                                __HIP_MEMORY_SCOPE_AGENT);
          const unsigned a1 = __hip_atomic_load(&arr[lane + 64], __ATOMIC_RELAXED,
                                                __HIP_MEMORY_SCOPE_AGENT);
          const unsigned a2 = __hip_atomic_load(&arr[lane + 128], __ATOMIC_RELAXED,
                                                __HIP_MEMORY_SCOPE_AGENT);
          const unsigned a3 = __hip_atomic_load(&arr[lane + 192], __ATOMIC_RELAXED,
                                                __HIP_MEMORY_SCOPE_AGENT);
          const bool ok = (a0 >= tgt) & (a1 >= tgt) & (a2 >= tgt) & (a3 >= tgt);
          if (__all(ok)) break;
          __builtin_amdgcn_s_sleep(1);
        }
      }
    }
    __syncthreads();   // other 15 waves park here while wave 0 runs the barrier
  }
}

// =============== f32 fallback (no workspace) ===============
__global__ __launch_bounds__(256, 2)
void step_f32(const float* __restrict__ K,
              const float* __restrict__ z_old, float* __restrict__ z_new,
              const float* __restrict__ omega_p, const float* __restrict__ dt_p) {
  const int tid = threadIdx.x;
  const int wave = tid >> 6, lane = tid & 63;
  const int row0 = blockIdx.x * 8;
  __shared__ float red[4][16];
  float ar[8] = {0, 0, 0, 0, 0, 0, 0, 0};
  float ai[8] = {0, 0, 0, 0, 0, 0, 0, 0};
  const int cbase = wave * 2048 + lane * 8;
#pragma unroll
  for (int it = 0; it < 4; ++it) {
    const int c = cbase + it * 512;
    const float4 zA = *(const float4*)(z_old + 2 * c + 0);
    const float4 zB = *(const float4*)(z_old + 2 * c + 4);
    const float4 zC = *(const float4*)(z_old + 2 * c + 8);
    const float4 zD = *(const float4*)(z_old + 2 * c + 12);
#pragma unroll
    for (int r = 0; r < 8; ++r) {
      const float* kp = K + (size_t)(row0 + r) * NN + c;
      const float4 ka = *(const float4*)kp;
      const float4 kb = *(const float4*)(kp + 4);
      float sr = ar[r], si = ai[r];
      sr = fmaf(ka.x, zA.x, sr); si = fmaf(ka.x, zA.y, si);
      sr = fmaf(ka.y, zA.z, sr); si = fmaf(ka.y, zA.w, si);
      sr = fmaf(ka.z, zB.x, sr); si = fmaf(ka.z, zB.y, si);
      sr = fmaf(ka.w, zB.z, sr); si = fmaf(ka.w, zB.w, si);
      sr = fmaf(kb.x, zC.x, sr); si = fmaf(kb.x, zC.y, si);
      sr = fmaf(kb.y, zC.z, sr); si = fmaf(kb.y, zC.w, si);
      sr = fmaf(kb.z, zD.x, sr); si = fmaf(kb.z, zD.y, si);
      sr = fmaf(kb.w, zD.z, sr); si = fmaf(kb.w, zD.w, si);
      ar[r] = sr; ai[r] = si;
    }
  }
#pragma unroll
  for (int off = 32; off > 0; off >>= 1) {
#pragma unroll
    for (int r = 0; r < 8; ++r) {
      ar[r] += __shfl_xor(ar[r], off);
      ai[r] += __shfl_xor(ai[r], off);
    }
  }
  if (lane == 0) {
#pragma unroll
    for (int r = 0; r < 8; ++r) {
      red[wave][2 * r + 0] = ar[r];
      red[wave][2 * r + 1] = ai[r];
    }
  }
  __syncthreads();
  if (tid < 8) {
    const float Wr = red[0][2 * tid] + red[1][2 * tid] + red[2][2 * tid] + red[3][2 * tid];
    const float Wi = red[0][2 * tid + 1] + red[1][2 * tid + 1] +
                     red[2][2 * tid + 1] + red[3][2 * tid + 1];
    const int row = row0 + tid;
    const float omega = *omega_p;
    const float dt = *dt_p;
    const float inv2n = 1.0f / (2.0f * (float)NN);
    const float zr = z_old[2 * row];
    const float zi = z_old[2 * row + 1];
    const float z2r = zr * zr - zi * zi;
    const float z2i = 2.0f * zr * zi;
    const float t1r = -inv2n * (Wr * z2r + Wi * z2i);
    const float t1i = -inv2n * (Wr * z2i - Wi * z2r);
    float nr = zr + dt * (t1r + omega * zr + inv2n * Wr);
    float ni = zi + dt * (t1i + omega * zi + inv2n * Wi);
    const float a = sqrtf(nr * nr + ni * ni);
    if (a >= CLAMP_V) { nr = nr / a * CLAMP_V; ni = ni / a * CLAMP_V; }
    z_new[2 * row] = nr;
    z_new[2 * row + 1] = ni;
  }
}

__global__ __launch_bounds__(256) void finalize_kernel(const float* __restrict__ z,
                                                       float* __restrict__ out) {
  int i = blockIdx.x * blockDim.x + threadIdx.x;
  if (i < NN) {
    float x = z[2 * i], y = z[2 * i + 1];
    float n = sqrtf(x * x + y * y);
    if (n >= CLAMP_V) { x = x / n * CLAMP_V; y = y / n * CLAMP_V; }
    out[2 * i] = x;
    out[2 * i + 1] = y;
  }
}

extern "C" void kernel_launch(void* const* d_in, const int* in_sizes, int n_in,
                              void* d_out, int out_size, void* d_ws, size_t ws_size,
                              hipStream_t stream) {
  const float* z_in = (const float*)d_in[0];      // [8192,2] f32
  const float* K = (const float*)d_in[1];         // [8192,8192] f32
  const float* omega_p = (const float*)d_in[2];   // scalar f32
  const float* dt_p = (const float*)d_in[3];      // scalar f32
  float* out = (float*)d_out;

  char* ws = (char*)d_ws;
  const size_t kq_bytes = (size_t)NN * WPR * sizeof(unsigned);  // 32 MiB
  const size_t sc_bytes = (size_t)NN * sizeof(float);           // 32 KiB
  const size_t plane = (size_t)NN;                              // 8 KiB per i8 plane
  const size_t need = kq_bytes + sc_bytes + 4 * plane + 2048;
  const bool use_q = ws_size >= need;

  if (use_q) {
    size_t off = 0;
    unsigned* Kq = (unsigned*)(ws + off); off += kq_bytes;
    float* scales = (float*)(ws + off); off += sc_bytes;
    signed char* q_re0 = (signed char*)(ws + off); off += plane;
    signed char* q_im0 = (signed char*)(ws + off); off += plane;
    signed char* q_re1 = (signed char*)(ws + off); off += plane;
    signed char* q_im1 = (signed char*)(ws + off); off += plane;
    float* scz = (float*)(ws + off); off += 64;
    unsigned* arr = (unsigned*)(ws + off);        // 256 barrier slots (1 KiB)

    quant4_kernel<<<NN, 256, 0, stream>>>(K, Kq, scales);
    prep_kernel<<<1, 256, 0, stream>>>(z_in, q_re0, q_im0, scz, arr);
    persist_kernel<<<NBLK, TPB, 0, stream>>>(Kq, scales, z_in,
                                             q_re0, q_im0, q_re1, q_im1,
                                             scz, omega_p, dt_p, out, arr);
  } else {
    float* zb0 = (float*)ws;
    float* zb1 = zb0 + NN * 2;
    const float* src = z_in;
    for (int s = 0; s < STEPS; ++s) {
      float* dst = (s & 1) ? zb1 : zb0;
      step_f32<<<NN / 8, 256, 0, stream>>>(K, src, dst, omega_p, dt_p);
      src = dst;
    }
    finalize_kernel<<<(NN + 255) / 256, 256, 0, stream>>>(src, out);
  }
}

// Round 3
// 771.777 us; speedup vs baseline: 1.8525x; 1.5870x over previous
//
#include <hip/hip_runtime.h>

#define NN 8192
#define STEPS 128
#define CLAMP_V 0.999f
#define WPR 1024   // packed 4-bit words per row (8192/8)
#define NBLK 256
#define TPB 1024

#if __has_builtin(__builtin_amdgcn_sdot4)
#define DOT4(a, b, c) __builtin_amdgcn_sdot4((int)(a), (int)(b), (c), false)
#else
__device__ __forceinline__ int dot4_fb(int a, int b, int c) {
#pragma unroll
  for (int i = 0; i < 4; ++i)
    c += ((int)(signed char)(a >> (8 * i))) * ((int)(signed char)(b >> (8 * i)));
  return c;
}
#define DOT4(a, b, c) dot4_fb((int)(a), (int)(b), (c))
#endif

#if __has_builtin(__builtin_amdgcn_perm)
#define PERM(a, b, s) __builtin_amdgcn_perm((a), (b), (s))
#else
__device__ __forceinline__ unsigned perm_fb(unsigned a, unsigned b, unsigned s) {
  unsigned long long v = ((unsigned long long)a << 32) | b;
  unsigned r = 0;
#pragma unroll
  for (int i = 0; i < 4; ++i) r |= ((unsigned)(v >> (8 * ((s >> (8 * i)) & 7))) & 0xFF) << (8 * i);
  return r;
}
#define PERM(a, b, s) perm_fb((a), (b), (s))
#endif

// =============== int4 quantization, dot4-friendly nibble order ===============
// word widx covers cols c0=8*widx .. c0+7. Nibble positions: {c0,c4,c1,c5,c2,c6,c3,c7}
// so lo=(w<<4)&0xF0F0F0F0 = {c0,c1,c2,c3}*16 and hi=w&0xF0F0F0F0 = {c4..c7}*16.
// scales[row] = rowmax/(7*16)
__global__ __launch_bounds__(256) void quant4_kernel(const float* __restrict__ K,
                                                     unsigned* __restrict__ Kq,
                                                     float* __restrict__ scales) {
  const int row = blockIdx.x;
  const int tid = threadIdx.x;
  const int wave = tid >> 6, lane = tid & 63;
  const size_t base = (size_t)row * NN;

  float4 va[4], vb[4];
  float mx = 0.f;
#pragma unroll
  for (int g = 0; g < 4; ++g) {
    const size_t o = base + (size_t)(g * 256 + tid) * 8;
    va[g] = *(const float4*)(K + o);
    vb[g] = *(const float4*)(K + o + 4);
    mx = fmaxf(mx, fmaxf(fmaxf(fabsf(va[g].x), fabsf(va[g].y)),
                         fmaxf(fabsf(va[g].z), fabsf(va[g].w))));
    mx = fmaxf(mx, fmaxf(fmaxf(fabsf(vb[g].x), fabsf(vb[g].y)),
                         fmaxf(fabsf(vb[g].z), fabsf(vb[g].w))));
  }
#pragma unroll
  for (int off = 32; off > 0; off >>= 1) mx = fmaxf(mx, __shfl_xor(mx, off));
  __shared__ float wm[4];
  if (lane == 0) wm[wave] = mx;
  __syncthreads();
  mx = fmaxf(fmaxf(wm[0], wm[1]), fmaxf(wm[2], wm[3]));

  const float inv = (mx > 0.f) ? 7.f / mx : 0.f;
  if (tid == 0) scales[row] = mx / 112.f;   // rowmax/(7*16)

#pragma unroll
  for (int g = 0; g < 4; ++g) {
    int qa[4], qb[4];
    const float a4[4] = {va[g].x, va[g].y, va[g].z, va[g].w};
    const float b4[4] = {vb[g].x, vb[g].y, vb[g].z, vb[g].w};
#pragma unroll
    for (int i = 0; i < 4; ++i) {
      qa[i] = max(-7, min(7, __float2int_rn(a4[i] * inv)));
      qb[i] = max(-7, min(7, __float2int_rn(b4[i] * inv)));
    }
    unsigned w = 0;
#pragma unroll
    for (int i = 0; i < 4; ++i) {
      w |= ((unsigned)(qa[i] & 0xF)) << (8 * i);        // c_i at nibble 2i
      w |= ((unsigned)(qb[i] & 0xF)) << (8 * i + 4);    // c_{4+i} at nibble 2i+1
    }
    Kq[(size_t)row * WPR + g * 256 + tid] = w;
  }
}

// =============== prep: build tagged plane_0; seed tz1 with impossible tag ===============
// Tagged word for pair p (rows 2p,2p+1): re0|im0<<8|re1<<16|im1<<24 | tag<<32.
// Thread t's buf[j] = z rows 32t+2j, 32t+2j+1 -> exactly pair p = 16t+j.
__global__ __launch_bounds__(256) void prep_kernel(const float* __restrict__ z,
                                                   unsigned long long* __restrict__ tz0,
                                                   unsigned long long* __restrict__ tz1,
                                                   float* __restrict__ scz) {
  const int tid = threadIdx.x;
  const int wave = tid >> 6, lane = tid & 63;
  float4 buf[16];
  float mx = 0.f;
#pragma unroll
  for (int j = 0; j < 16; ++j) {
    buf[j] = *(const float4*)(z + tid * 64 + j * 4);
    mx = fmaxf(mx, fmaxf(fmaxf(fabsf(buf[j].x), fabsf(buf[j].y)),
                         fmaxf(fabsf(buf[j].z), fabsf(buf[j].w))));
  }
#pragma unroll
  for (int off = 32; off > 0; off >>= 1) mx = fmaxf(mx, __shfl_xor(mx, off));
  __shared__ float wm[4];
  if (lane == 0) wm[wave] = mx;
  __syncthreads();
  mx = fmaxf(fmaxf(wm[0], wm[1]), fmaxf(wm[2], wm[3]));
  const float q = (mx > 0.f) ? 127.f / mx : 0.f;
  if (tid == 0) scz[0] = mx / 127.f;
#pragma unroll
  for (int j = 0; j < 16; ++j) {
    const int p = tid * 16 + j;
    const unsigned a = (unsigned)(max(-127, min(127, __float2int_rn(buf[j].x * q)))) & 0xFFu;
    const unsigned b = (unsigned)(max(-127, min(127, __float2int_rn(buf[j].y * q)))) & 0xFFu;
    const unsigned c = (unsigned)(max(-127, min(127, __float2int_rn(buf[j].z * q)))) & 0xFFu;
    const unsigned d = (unsigned)(max(-127, min(127, __float2int_rn(buf[j].w * q)))) & 0xFFu;
    tz0[p] = (unsigned long long)(a | (b << 8) | (c << 16) | (d << 24));  // tag 0
    tz1[p] = 0xFFFFFFFFull << 32;  // tag never matched (expected odd tags 1..127)
  }
}

// =============== persistent kernel: no grid barrier — tag rides with data ===============
// 256 blocks x 1024 thr (16 waves). Wave w of block b owns rows 32b+2w, 32b+2w+1
// = pair 16b+w. Per step: poll own 64-word LDS chunk (4 tagged u64/lane) until
// tags==s, unpack via v_perm into the plane layout, sync, dot (K in VGPRs),
// update, store one tagged u64 (tag s+1) to the other parity array.
// Safety: producer stores tag s+2 only after its block's syncthreads for step
// s+1, which requires all its 16 waves to have seen EVERY pair tagged s+1
// (their chunks cover all 4096 pairs) => every block finished reading plane_s.
// So a tag-s word is never clobbered while needed; exact-match polls, relaxed
// atomics only, no fences, no RMW.
__global__ __launch_bounds__(TPB, 4)
void persist_kernel(const unsigned* __restrict__ Kq, const float* __restrict__ scales,
                    const float* __restrict__ z_in,
                    unsigned long long* __restrict__ tz0,
                    unsigned long long* __restrict__ tz1,
                    const float* __restrict__ scz_p,
                    const float* __restrict__ omega_p, const float* __restrict__ dt_p,
                    float* __restrict__ out) {
  const int tid = threadIdx.x;
  const int wave = tid >> 6, lane = tid & 63;
  const int rowA = blockIdx.x * 32 + wave * 2;
  const int rowB = rowA + 1;
  const int pair = blockIdx.x * 16 + wave;

  __shared__ unsigned long long lds_re[1024];   // 8 KiB re plane (8 i8/row per u64)
  __shared__ unsigned long long lds_im[1024];   // 8 KiB im plane

  // ---- one-time: K rows into registers, pre-unpacked; asm-pin to stop remat ----
  unsigned kLoA[16], kHiA[16], kLoB[16], kHiB[16];
  {
    const unsigned* kpA = Kq + (size_t)rowA * WPR + lane;
    const unsigned* kpB = Kq + (size_t)rowB * WPR + lane;
#pragma unroll
    for (int seg = 0; seg < 16; ++seg) {
      const unsigned wA = kpA[seg * 64];
      const unsigned wB = kpB[seg * 64];
      kLoA[seg] = (wA << 4) & 0xF0F0F0F0u;
      kHiA[seg] = wA & 0xF0F0F0F0u;
      kLoB[seg] = (wB << 4) & 0xF0F0F0F0u;
      kHiB[seg] = wB & 0xF0F0F0F0u;
      asm volatile("" : "+v"(kLoA[seg]), "+v"(kHiA[seg]),
                        "+v"(kLoB[seg]), "+v"(kHiB[seg]));
    }
  }

  // ---- f32 z state for owned rows lives (lane-uniform) in registers ----
  float zrA = z_in[2 * rowA], ziA = z_in[2 * rowA + 1];
  float zrB = z_in[2 * rowB], ziB = z_in[2 * rowB + 1];
  const float scA = scales[rowA], scB = scales[rowB];
  const float omega = *omega_p, dt = *dt_p;
  const float inv2n = 1.0f / (2.0f * (float)NN);
  const float sz0 = *scz_p;

  const int j = wave * 64 + lane;   // LDS word (and pair group 4j..4j+3) this lane stages

  for (int s = 0; s < STEPS; ++s) {
    const unsigned long long* tzc = (s & 1) ? tz1 : tz0;   // plane_s
    const unsigned tagw = (unsigned)s;

    // ---- poll own chunk; the poll IS the load ----
    unsigned long long t0, t1, t2, t3;
    {
      const unsigned long long* p4 = tzc + 4 * j;
      for (;;) {
        t0 = __hip_atomic_load(p4 + 0, __ATOMIC_RELAXED, __HIP_MEMORY_SCOPE_AGENT);
        t1 = __hip_atomic_load(p4 + 1, __ATOMIC_RELAXED, __HIP_MEMORY_SCOPE_AGENT);
        t2 = __hip_atomic_load(p4 + 2, __ATOMIC_RELAXED, __HIP_MEMORY_SCOPE_AGENT);
        t3 = __hip_atomic_load(p4 + 3, __ATOMIC_RELAXED, __HIP_MEMORY_SCOPE_AGENT);
        const bool ok = ((unsigned)(t0 >> 32) == tagw) & ((unsigned)(t1 >> 32) == tagw) &
                        ((unsigned)(t2 >> 32) == tagw) & ((unsigned)(t3 >> 32) == tagw);
        if (__all(ok)) break;
        __builtin_amdgcn_s_sleep(1);
      }
    }
    // ---- unpack {re,im,re,im} x4 pairs -> plane words (byte i = row 8j+i) ----
    {
      const unsigned lo0 = (unsigned)t0, lo1 = (unsigned)t1;
      const unsigned lo2 = (unsigned)t2, lo3 = (unsigned)t3;
      const unsigned re0123 = PERM(lo1, lo0, 0x06040200u);
      const unsigned re4567 = PERM(lo3, lo2, 0x06040200u);
      const unsigned im0123 = PERM(lo1, lo0, 0x07050301u);
      const unsigned im4567 = PERM(lo3, lo2, 0x07050301u);
      lds_re[j] = (unsigned long long)re0123 | ((unsigned long long)re4567 << 32);
      lds_im[j] = (unsigned long long)im0123 | ((unsigned long long)im4567 << 32);
    }
    __syncthreads();   // full plane staged

    int srA = 0, siA = 0, srB = 0, siB = 0;
#pragma unroll
    for (int seg = 0; seg < 16; ++seg) {
      const unsigned long long zr = lds_re[seg * 64 + lane];  // 8B stride: conflict-free
      const unsigned long long zi = lds_im[seg * 64 + lane];
      const unsigned zrl = (unsigned)zr, zrh = (unsigned)(zr >> 32);
      const unsigned zil = (unsigned)zi, zih = (unsigned)(zi >> 32);
      srA = DOT4(kLoA[seg], zrl, srA); srA = DOT4(kHiA[seg], zrh, srA);
      siA = DOT4(kLoA[seg], zil, siA); siA = DOT4(kHiA[seg], zih, siA);
      srB = DOT4(kLoB[seg], zrl, srB); srB = DOT4(kHiB[seg], zrh, srB);
      siB = DOT4(kLoB[seg], zil, siB); siB = DOT4(kHiB[seg], zih, siB);
    }

    // exact integer wave butterfly -> lane-uniform sums
#pragma unroll
    for (int off = 32; off > 0; off >>= 1) {
      srA += __shfl_xor(srA, off); siA += __shfl_xor(siA, off);
      srB += __shfl_xor(srB, off); siB += __shfl_xor(siB, off);
    }

    // ---- update (lane-uniform), identical math to previous rounds ----
    const float sz = (s == 0) ? sz0 : (1.f / 127.f);
    float nrA, niA, nrB, niB;
    {
      const float fac = scA * sz;
      const float Wr = (float)srA * fac, Wi = (float)siA * fac;
      const float z2r = zrA * zrA - ziA * ziA;
      const float z2i = 2.0f * zrA * ziA;
      const float t1r = -inv2n * (Wr * z2r + Wi * z2i);
      const float t1i = -inv2n * (Wr * z2i - Wi * z2r);
      nrA = zrA + dt * (t1r + omega * zrA + inv2n * Wr);
      niA = ziA + dt * (t1i + omega * ziA + inv2n * Wi);
      const float a = sqrtf(nrA * nrA + niA * niA);
      if (a >= CLAMP_V) { nrA = nrA / a * CLAMP_V; niA = niA / a * CLAMP_V; }
    }
    {
      const float fac = scB * sz;
      const float Wr = (float)srB * fac, Wi = (float)siB * fac;
      const float z2r = zrB * zrB - ziB * ziB;
      const float z2i = 2.0f * zrB * ziB;
      const float t1r = -inv2n * (Wr * z2r + Wi * z2i);
      const float t1i = -inv2n * (Wr * z2i - Wi * z2r);
      nrB = zrB + dt * (t1r + omega * zrB + inv2n * Wr);
      niB = ziB + dt * (t1i + omega * ziB + inv2n * Wi);
      const float a = sqrtf(nrB * nrB + niB * niB);
      if (a >= CLAMP_V) { nrB = nrB / a * CLAMP_V; niB = niB / a * CLAMP_V; }
    }
    zrA = nrA; ziA = niA; zrB = nrB; ziB = niB;

    if (s == STEPS - 1) {
      if (lane == 0) {
        float frA = nrA, fiA = niA, frB = nrB, fiB = niB;
        const float n2 = sqrtf(frA * frA + fiA * fiA);
        if (n2 >= CLAMP_V) { frA = frA / n2 * CLAMP_V; fiA = fiA / n2 * CLAMP_V; }
        const float n3 = sqrtf(frB * frB + fiB * fiB);
        if (n3 >= CLAMP_V) { frB = frB / n3 * CLAMP_V; fiB = fiB / n3 * CLAMP_V; }
        float4 o; o.x = frA; o.y = fiA; o.z = frB; o.w = fiB;
        *(float4*)(out + 2 * rowA) = o;   // rows A,B contiguous, 16B-aligned
      }
    } else if (lane == 0) {
      const unsigned a = (unsigned)__float2int_rn(nrA * 127.f) & 0xFFu;
      const unsigned b = (unsigned)__float2int_rn(niA * 127.f) & 0xFFu;
      const unsigned c = (unsigned)__float2int_rn(nrB * 127.f) & 0xFFu;
      const unsigned d = (unsigned)__float2int_rn(niB * 127.f) & 0xFFu;
      const unsigned long long w =
          (unsigned long long)(a | (b << 8) | (c << 16) | (d << 24)) |
          ((unsigned long long)(unsigned)(s + 1) << 32);
      __hip_atomic_store(((s & 1) ? tz0 : tz1) + pair, w,
                         __ATOMIC_RELAXED, __HIP_MEMORY_SCOPE_AGENT);
    }
    __syncthreads();   // LDS reuse guard; also the sync the safety proof relies on
  }
}

// =============== f32 fallback (no workspace) ===============
__global__ __launch_bounds__(256, 2)
void step_f32(const float* __restrict__ K,
              const float* __restrict__ z_old, float* __restrict__ z_new,
              const float* __restrict__ omega_p, const float* __restrict__ dt_p) {
  const int tid = threadIdx.x;
  const int wave = tid >> 6, lane = tid & 63;
  const int row0 = blockIdx.x * 8;
  __shared__ float red[4][16];
  float ar[8] = {0, 0, 0, 0, 0, 0, 0, 0};
  float ai[8] = {0, 0, 0, 0, 0, 0, 0, 0};
  const int cbase = wave * 2048 + lane * 8;
#pragma unroll
  for (int it = 0; it < 4; ++it) {
    const int c = cbase + it * 512;
    const float4 zA = *(const float4*)(z_old + 2 * c + 0);
    const float4 zB = *(const float4*)(z_old + 2 * c + 4);
    const float4 zC = *(const float4*)(z_old + 2 * c + 8);
    const float4 zD = *(const float4*)(z_old + 2 * c + 12);
#pragma unroll
    for (int r = 0; r < 8; ++r) {
      const float* kp = K + (size_t)(row0 + r) * NN + c;
      const float4 ka = *(const float4*)kp;
      const float4 kb = *(const float4*)(kp + 4);
      float sr = ar[r], si = ai[r];
      sr = fmaf(ka.x, zA.x, sr); si = fmaf(ka.x, zA.y, si);
      sr = fmaf(ka.y, zA.z, sr); si = fmaf(ka.y, zA.w, si);
      sr = fmaf(ka.z, zB.x, sr); si = fmaf(ka.z, zB.y, si);
      sr = fmaf(ka.w, zB.z, sr); si = fmaf(ka.w, zB.w, si);
      sr = fmaf(kb.x, zC.x, sr); si = fmaf(kb.x, zC.y, si);
      sr = fmaf(kb.y, zC.z, sr); si = fmaf(kb.y, zC.w, si);
      sr = fmaf(kb.z, zD.x, sr); si = fmaf(kb.z, zD.y, si);
      sr = fmaf(kb.w, zD.z, sr); si = fmaf(kb.w, zD.w, si);
      ar[r] = sr; ai[r] = si;
    }
  }
#pragma unroll
  for (int off = 32; off > 0; off >>= 1) {
#pragma unroll
    for (int r = 0; r < 8; ++r) {
      ar[r] += __shfl_xor(ar[r], off);
      ai[r] += __shfl_xor(ai[r], off);
    }
  }
  if (lane == 0) {
#pragma unroll
    for (int r = 0; r < 8; ++r) {
      red[wave][2 * r + 0] = ar[r];
      red[wave][2 * r + 1] = ai[r];
    }
  }
  __syncthreads();
  if (tid < 8) {
    const float Wr = red[0][2 * tid] + red[1][2 * tid] + red[2][2 * tid] + red[3][2 * tid];
    const float Wi = red[0][2 * tid + 1] + red[1][2 * tid + 1] +
                     red[2][2 * tid + 1] + red[3][2 * tid + 1];
    const int row = row0 + tid;
    const float omega = *omega_p;
    const float dt = *dt_p;
    const float inv2n = 1.0f / (2.0f * (float)NN);
    const float zr = z_old[2 * row];
    const float zi = z_old[2 * row + 1];
    const float z2r = zr * zr - zi * zi;
    const float z2i = 2.0f * zr * zi;
    const float t1r = -inv2n * (Wr * z2r + Wi * z2i);
    const float t1i = -inv2n * (Wr * z2i - Wi * z2r);
    float nr = zr + dt * (t1r + omega * zr + inv2n * Wr);
    float ni = zi + dt * (t1i + omega * zi + inv2n * Wi);
    const float a = sqrtf(nr * nr + ni * ni);
    if (a >= CLAMP_V) { nr = nr / a * CLAMP_V; ni = ni / a * CLAMP_V; }
    z_new[2 * row] = nr;
    z_new[2 * row + 1] = ni;
  }
}

__global__ __launch_bounds__(256) void finalize_kernel(const float* __restrict__ z,
                                                       float* __restrict__ out) {
  int i = blockIdx.x * blockDim.x + threadIdx.x;
  if (i < NN) {
    float x = z[2 * i], y = z[2 * i + 1];
    float n = sqrtf(x * x + y * y);
    if (n >= CLAMP_V) { x = x / n * CLAMP_V; y = y / n * CLAMP_V; }
    out[2 * i] = x;
    out[2 * i + 1] = y;
  }
}

extern "C" void kernel_launch(void* const* d_in, const int* in_sizes, int n_in,
                              void* d_out, int out_size, void* d_ws, size_t ws_size,
                              hipStream_t stream) {
  const float* z_in = (const float*)d_in[0];      // [8192,2] f32
  const float* K = (const float*)d_in[1];         // [8192,8192] f32
  const float* omega_p = (const float*)d_in[2];   // scalar f32
  const float* dt_p = (const float*)d_in[3];      // scalar f32
  float* out = (float*)d_out;

  char* ws = (char*)d_ws;
  const size_t kq_bytes = (size_t)NN * WPR * sizeof(unsigned);          // 32 MiB
  const size_t sc_bytes = (size_t)NN * sizeof(float);                   // 32 KiB
  const size_t tz_bytes = (size_t)(NN / 2) * sizeof(unsigned long long);// 32 KiB each
  const size_t need = kq_bytes + sc_bytes + 2 * tz_bytes + 256;
  const bool use_q = ws_size >= need;

  if (use_q) {
    size_t off = 0;
    unsigned* Kq = (unsigned*)(ws + off); off += kq_bytes;
    float* scales = (float*)(ws + off); off += sc_bytes;
    unsigned long long* tz0 = (unsigned long long*)(ws + off); off += tz_bytes;
    unsigned long long* tz1 = (unsigned long long*)(ws + off); off += tz_bytes;
    float* scz = (float*)(ws + off);

    quant4_kernel<<<NN, 256, 0, stream>>>(K, Kq, scales);
    prep_kernel<<<1, 256, 0, stream>>>(z_in, tz0, tz1, scz);
    persist_kernel<<<NBLK, TPB, 0, stream>>>(Kq, scales, z_in, tz0, tz1,
                                             scz, omega_p, dt_p, out);
  } else {
    float* zb0 = (float*)ws;
    float* zb1 = zb0 + NN * 2;
    const float* src = z_in;
    for (int s = 0; s < STEPS; ++s) {
      float* dst = (s & 1) ? zb1 : zb0;
      step_f32<<<NN / 8, 256, 0, stream>>>(K, src, dst, omega_p, dt_p);
      src = dst;
    }
    finalize_kernel<<<(NN + 255) / 256, 256, 0, stream>>>(src, out);
  }
}

// Round 4
// 735.568 us; speedup vs baseline: 1.9437x; 1.0492x over previous
//
#include <hip/hip_runtime.h>

#define NN 8192
#define STEPS 128
#define CLAMP_V 0.999f
#define WPR 1024   // packed 4-bit words per row (8192/8)
#define NBLK 256
#define TPB 1024

#if __has_builtin(__builtin_amdgcn_sdot4)
#define DOT4(a, b, c) __builtin_amdgcn_sdot4((int)(a), (int)(b), (c), false)
#else
__device__ __forceinline__ int dot4_fb(int a, int b, int c) {
#pragma unroll
  for (int i = 0; i < 4; ++i)
    c += ((int)(signed char)(a >> (8 * i))) * ((int)(signed char)(b >> (8 * i)));
  return c;
}
#define DOT4(a, b, c) dot4_fb((int)(a), (int)(b), (c))
#endif

#if __has_builtin(__builtin_amdgcn_perm)
#define PERM(a, b, s) __builtin_amdgcn_perm((a), (b), (s))
#else
__device__ __forceinline__ unsigned perm_fb(unsigned a, unsigned b, unsigned s) {
  unsigned long long v = ((unsigned long long)a << 32) | b;
  unsigned r = 0;
#pragma unroll
  for (int i = 0; i < 4; ++i) r |= ((unsigned)(v >> (8 * ((s >> (8 * i)) & 7))) & 0xFF) << (8 * i);
  return r;
}
#define PERM(a, b, s) perm_fb((a), (b), (s))
#endif

// =============== int4 quantization, dot4-friendly nibble order ===============
// word widx covers cols c0=8*widx .. c0+7. Nibble positions: {c0,c4,c1,c5,c2,c6,c3,c7}
// so lo=(w<<4)&0xF0F0F0F0 = {c0,c1,c2,c3}*16 and hi=w&0xF0F0F0F0 = {c4..c7}*16.
// scales[row] = rowmax/(7*16)
__global__ __launch_bounds__(256) void quant4_kernel(const float* __restrict__ K,
                                                     unsigned* __restrict__ Kq,
                                                     float* __restrict__ scales) {
  const int row = blockIdx.x;
  const int tid = threadIdx.x;
  const int wave = tid >> 6, lane = tid & 63;
  const size_t base = (size_t)row * NN;

  float4 va[4], vb[4];
  float mx = 0.f;
#pragma unroll
  for (int g = 0; g < 4; ++g) {
    const size_t o = base + (size_t)(g * 256 + tid) * 8;
    va[g] = *(const float4*)(K + o);
    vb[g] = *(const float4*)(K + o + 4);
    mx = fmaxf(mx, fmaxf(fmaxf(fabsf(va[g].x), fabsf(va[g].y)),
                         fmaxf(fabsf(va[g].z), fabsf(va[g].w))));
    mx = fmaxf(mx, fmaxf(fmaxf(fabsf(vb[g].x), fabsf(vb[g].y)),
                         fmaxf(fabsf(vb[g].z), fabsf(vb[g].w))));
  }
#pragma unroll
  for (int off = 32; off > 0; off >>= 1) mx = fmaxf(mx, __shfl_xor(mx, off));
  __shared__ float wm[4];
  if (lane == 0) wm[wave] = mx;
  __syncthreads();
  mx = fmaxf(fmaxf(wm[0], wm[1]), fmaxf(wm[2], wm[3]));

  const float inv = (mx > 0.f) ? 7.f / mx : 0.f;
  if (tid == 0) scales[row] = mx / 112.f;   // rowmax/(7*16)

#pragma unroll
  for (int g = 0; g < 4; ++g) {
    int qa[4], qb[4];
    const float a4[4] = {va[g].x, va[g].y, va[g].z, va[g].w};
    const float b4[4] = {vb[g].x, vb[g].y, vb[g].z, vb[g].w};
#pragma unroll
    for (int i = 0; i < 4; ++i) {
      qa[i] = max(-7, min(7, __float2int_rn(a4[i] * inv)));
      qb[i] = max(-7, min(7, __float2int_rn(b4[i] * inv)));
    }
    unsigned w = 0;
#pragma unroll
    for (int i = 0; i < 4; ++i) {
      w |= ((unsigned)(qa[i] & 0xF)) << (8 * i);        // c_i at nibble 2i
      w |= ((unsigned)(qb[i] & 0xF)) << (8 * i + 4);    // c_{4+i} at nibble 2i+1
    }
    Kq[(size_t)row * WPR + g * 256 + tid] = w;
  }
}

// =============== prep: build tagged plane_0; seed tz1 with impossible tag ===============
// Tagged word for pair p (rows 2p,2p+1): re0|im0<<8|re1<<16|im1<<24 | tag<<32.
__global__ __launch_bounds__(256) void prep_kernel(const float* __restrict__ z,
                                                   unsigned long long* __restrict__ tz0,
                                                   unsigned long long* __restrict__ tz1,
                                                   float* __restrict__ scz) {
  const int tid = threadIdx.x;
  const int wave = tid >> 6, lane = tid & 63;
  float4 buf[16];
  float mx = 0.f;
#pragma unroll
  for (int j = 0; j < 16; ++j) {
    buf[j] = *(const float4*)(z + tid * 64 + j * 4);
    mx = fmaxf(mx, fmaxf(fmaxf(fabsf(buf[j].x), fabsf(buf[j].y)),
                         fmaxf(fabsf(buf[j].z), fabsf(buf[j].w))));
  }
#pragma unroll
  for (int off = 32; off > 0; off >>= 1) mx = fmaxf(mx, __shfl_xor(mx, off));
  __shared__ float wm[4];
  if (lane == 0) wm[wave] = mx;
  __syncthreads();
  mx = fmaxf(fmaxf(wm[0], wm[1]), fmaxf(wm[2], wm[3]));
  const float q = (mx > 0.f) ? 127.f / mx : 0.f;
  if (tid == 0) scz[0] = mx / 127.f;
#pragma unroll
  for (int j = 0; j < 16; ++j) {
    const int p = tid * 16 + j;
    const unsigned a = (unsigned)(max(-127, min(127, __float2int_rn(buf[j].x * q)))) & 0xFFu;
    const unsigned b = (unsigned)(max(-127, min(127, __float2int_rn(buf[j].y * q)))) & 0xFFu;
    const unsigned c = (unsigned)(max(-127, min(127, __float2int_rn(buf[j].z * q)))) & 0xFFu;
    const unsigned d = (unsigned)(max(-127, min(127, __float2int_rn(buf[j].w * q)))) & 0xFFu;
    tz0[p] = (unsigned long long)(a | (b << 8) | (c << 16) | (d << 24));  // tag 0
    tz1[p] = 0xFFFFFFFFull << 32;  // tag never matched (expected odd tags 1..127)
  }
}

// =============== persistent kernel: tag rides with data; throttled polls ===============
// 256 blocks x 1024 thr (16 waves). Wave w of block b owns rows 32b+2w, 32b+2w+1
// = pair 16b+w. Poll own 64-word chunk with SELECTIVE re-read (only untagged
// words) + exponential s_sleep backoff (64..512 cyc) to keep aggregate poll
// traffic far below LLC service rate. Unpack via v_perm, stage LDS, barrier,
// dot (K pre-unpacked in regs), butterfly, LANE-SPLIT update (even lanes row A,
// odd lanes row B — identical op order => bit-identical), shfl-combine, lane 0
// stores one tagged u64.
// Safety induction (unchanged): a store of tag s+2 happens after this block's
// post-staging barrier of step s+1, which certifies ALL 4096 pairs tagged s+1,
// hence every producer (and thus every block) finished reading plane_s.
__global__ __launch_bounds__(TPB, 4)
void persist_kernel(const unsigned* __restrict__ Kq, const float* __restrict__ scales,
                    const float* __restrict__ z_in,
                    unsigned long long* __restrict__ tz0,
                    unsigned long long* __restrict__ tz1,
                    const float* __restrict__ scz_p,
                    const float* __restrict__ omega_p, const float* __restrict__ dt_p,
                    float* __restrict__ out) {
  const int tid = threadIdx.x;
  const int wave = tid >> 6, lane = tid & 63;
  const int rowA = blockIdx.x * 32 + wave * 2;
  const int rowB = rowA + 1;
  const int pair = blockIdx.x * 16 + wave;

  __shared__ unsigned long long lds_re[1024];   // 8 KiB re plane (8 i8/row per u64)
  __shared__ unsigned long long lds_im[1024];   // 8 KiB im plane

  // ---- one-time: K rows into registers, pre-unpacked; asm-pin to stop remat ----
  unsigned kLoA[16], kHiA[16], kLoB[16], kHiB[16];
  {
    const unsigned* kpA = Kq + (size_t)rowA * WPR + lane;
    const unsigned* kpB = Kq + (size_t)rowB * WPR + lane;
#pragma unroll
    for (int seg = 0; seg < 16; ++seg) {
      const unsigned wA = kpA[seg * 64];
      const unsigned wB = kpB[seg * 64];
      kLoA[seg] = (wA << 4) & 0xF0F0F0F0u;
      kHiA[seg] = wA & 0xF0F0F0F0u;
      kLoB[seg] = (wB << 4) & 0xF0F0F0F0u;
      kHiB[seg] = wB & 0xF0F0F0F0u;
      asm volatile("" : "+v"(kLoA[seg]), "+v"(kHiA[seg]),
                        "+v"(kLoB[seg]), "+v"(kHiB[seg]));
    }
  }

  // ---- per-lane z state: even lanes own row A, odd lanes own row B ----
  const int isB = lane & 1;
  float zr_s = z_in[2 * rowA + 2 * isB];
  float zi_s = z_in[2 * rowA + 2 * isB + 1];
  const float mySc = scales[rowA + isB];
  const float omega = *omega_p, dt = *dt_p;
  const float inv2n = 1.0f / (2.0f * (float)NN);
  const float sz0 = *scz_p;

  const int j = wave * 64 + lane;   // LDS word (pairs 4j..4j+3) this lane stages

  for (int s = 0; s < STEPS; ++s) {
    const unsigned long long* tzc = (s & 1) ? tz1 : tz0;   // plane_s
    const unsigned tagw = (unsigned)s;

    // ---- throttled poll: selective re-read + backoff; the poll IS the load ----
    unsigned long long t0 = 0, t1 = 0, t2 = 0, t3 = 0;
    {
      const unsigned long long* p4 = tzc + 4 * j;
      bool k0 = false, k1 = false, k2 = false, k3 = false;
      int it = 0;
      for (;;) {
        if (!k0) { t0 = __hip_atomic_load(p4 + 0, __ATOMIC_RELAXED, __HIP_MEMORY_SCOPE_AGENT);
                   k0 = ((unsigned)(t0 >> 32) == tagw); }
        if (!k1) { t1 = __hip_atomic_load(p4 + 1, __ATOMIC_RELAXED, __HIP_MEMORY_SCOPE_AGENT);
                   k1 = ((unsigned)(t1 >> 32) == tagw); }
        if (!k2) { t2 = __hip_atomic_load(p4 + 2, __ATOMIC_RELAXED, __HIP_MEMORY_SCOPE_AGENT);
                   k2 = ((unsigned)(t2 >> 32) == tagw); }
        if (!k3) { t3 = __hip_atomic_load(p4 + 3, __ATOMIC_RELAXED, __HIP_MEMORY_SCOPE_AGENT);
                   k3 = ((unsigned)(t3 >> 32) == tagw); }
        if (__all(k0 && k1 && k2 && k3)) break;
        if (it == 0)      __builtin_amdgcn_s_sleep(1);   // ~64 cyc
        else if (it < 3)  __builtin_amdgcn_s_sleep(4);   // ~256 cyc
        else              __builtin_amdgcn_s_sleep(8);   // ~512 cyc cap
        ++it;
      }
    }
    // ---- unpack {re,im,re,im} x4 pairs -> plane words (byte i = row 8j+i) ----
    {
      const unsigned lo0 = (unsigned)t0, lo1 = (unsigned)t1;
      const unsigned lo2 = (unsigned)t2, lo3 = (unsigned)t3;
      const unsigned re0123 = PERM(lo1, lo0, 0x06040200u);
      const unsigned re4567 = PERM(lo3, lo2, 0x06040200u);
      const unsigned im0123 = PERM(lo1, lo0, 0x07050301u);
      const unsigned im4567 = PERM(lo3, lo2, 0x07050301u);
      lds_re[j] = (unsigned long long)re0123 | ((unsigned long long)re4567 << 32);
      lds_im[j] = (unsigned long long)im0123 | ((unsigned long long)im4567 << 32);
    }
    __syncthreads();   // full plane staged (load-bearing barrier for safety proof)

    int srA = 0, siA = 0, srB = 0, siB = 0;
#pragma unroll
    for (int seg = 0; seg < 16; ++seg) {
      const unsigned long long zr = lds_re[seg * 64 + lane];  // 8B stride: conflict-free
      const unsigned long long zi = lds_im[seg * 64 + lane];
      const unsigned zrl = (unsigned)zr, zrh = (unsigned)(zr >> 32);
      const unsigned zil = (unsigned)zi, zih = (unsigned)(zi >> 32);
      srA = DOT4(kLoA[seg], zrl, srA); srA = DOT4(kHiA[seg], zrh, srA);
      siA = DOT4(kLoA[seg], zil, siA); siA = DOT4(kHiA[seg], zih, siA);
      srB = DOT4(kLoB[seg], zrl, srB); srB = DOT4(kHiB[seg], zrh, srB);
      siB = DOT4(kLoB[seg], zil, siB); siB = DOT4(kHiB[seg], zih, siB);
    }

    // exact integer wave butterfly -> lane-uniform sums
#pragma unroll
    for (int off = 32; off > 0; off >>= 1) {
      srA += __shfl_xor(srA, off); siA += __shfl_xor(siA, off);
      srB += __shfl_xor(srB, off); siB += __shfl_xor(siB, off);
    }

    // ---- lane-split update: even lanes row A, odd lanes row B (same op order) ----
    const int sr = isB ? srB : srA;
    const int si = isB ? siB : siA;
    const float sz = (s == 0) ? sz0 : (1.f / 127.f);
    const float fac = mySc * sz;
    const float Wr = (float)sr * fac, Wi = (float)si * fac;
    const float z2r = zr_s * zr_s - zi_s * zi_s;
    const float z2i = 2.0f * zr_s * zi_s;
    const float t1r = -inv2n * (Wr * z2r + Wi * z2i);
    const float t1i = -inv2n * (Wr * z2i - Wi * z2r);
    float nr = zr_s + dt * (t1r + omega * zr_s + inv2n * Wr);
    float ni = zi_s + dt * (t1i + omega * zi_s + inv2n * Wi);
    const float a = sqrtf(nr * nr + ni * ni);
    if (a >= CLAMP_V) { nr = nr / a * CLAMP_V; ni = ni / a * CLAMP_V; }
    zr_s = nr; zi_s = ni;

    if (s == STEPS - 1) {
      float fr = nr, fi = ni;
      const float n2 = sqrtf(fr * fr + fi * fi);
      if (n2 >= CLAMP_V) { fr = fr / n2 * CLAMP_V; fi = fi / n2 * CLAMP_V; }
      const float frB = __shfl(fr, 1);
      const float fiB = __shfl(fi, 1);
      if (lane == 0) {
        float4 o; o.x = fr; o.y = fi; o.z = frB; o.w = fiB;
        *(float4*)(out + 2 * rowA) = o;   // rows A,B contiguous, 16B-aligned
      }
    } else {
      const unsigned pr = (unsigned)__float2int_rn(nr * 127.f) & 0xFFu;
      const unsigned pi = (unsigned)__float2int_rn(ni * 127.f) & 0xFFu;
      const unsigned half = pr | (pi << 8);              // even: A bytes, odd: B bytes
      const unsigned other = __shfl_xor(half, 1);
      if (lane == 0) {
        const unsigned long long w =
            (unsigned long long)(half | (other << 16)) |
            ((unsigned long long)(unsigned)(s + 1) << 32);
        __hip_atomic_store(((s & 1) ? tz0 : tz1) + pair, w,
                           __ATOMIC_RELAXED, __HIP_MEMORY_SCOPE_AGENT);
      }
    }
    __syncthreads();   // LDS reuse guard
  }
}

// =============== f32 fallback (no workspace) ===============
__global__ __launch_bounds__(256, 2)
void step_f32(const float* __restrict__ K,
              const float* __restrict__ z_old, float* __restrict__ z_new,
              const float* __restrict__ omega_p, const float* __restrict__ dt_p) {
  const int tid = threadIdx.x;
  const int wave = tid >> 6, lane = tid & 63;
  const int row0 = blockIdx.x * 8;
  __shared__ float red[4][16];
  float ar[8] = {0, 0, 0, 0, 0, 0, 0, 0};
  float ai[8] = {0, 0, 0, 0, 0, 0, 0, 0};
  const int cbase = wave * 2048 + lane * 8;
#pragma unroll
  for (int it = 0; it < 4; ++it) {
    const int c = cbase + it * 512;
    const float4 zA = *(const float4*)(z_old + 2 * c + 0);
    const float4 zB = *(const float4*)(z_old + 2 * c + 4);
    const float4 zC = *(const float4*)(z_old + 2 * c + 8);
    const float4 zD = *(const float4*)(z_old + 2 * c + 12);
#pragma unroll
    for (int r = 0; r < 8; ++r) {
      const float* kp = K + (size_t)(row0 + r) * NN + c;
      const float4 ka = *(const float4*)kp;
      const float4 kb = *(const float4*)(kp + 4);
      float sr = ar[r], si = ai[r];
      sr = fmaf(ka.x, zA.x, sr); si = fmaf(ka.x, zA.y, si);
      sr = fmaf(ka.y, zA.z, sr); si = fmaf(ka.y, zA.w, si);
      sr = fmaf(ka.z, zB.x, sr); si = fmaf(ka.z, zB.y, si);
      sr = fmaf(ka.w, zB.z, sr); si = fmaf(ka.w, zB.w, si);
      sr = fmaf(kb.x, zC.x, sr); si = fmaf(kb.x, zC.y, si);
      sr = fmaf(kb.y, zC.z, sr); si = fmaf(kb.y, zC.w, si);
      sr = fmaf(kb.z, zD.x, sr); si = fmaf(kb.z, zD.y, si);
      sr = fmaf(kb.w, zD.z, sr); si = fmaf(kb.w, zD.w, si);
      ar[r] = sr; ai[r] = si;
    }
  }
#pragma unroll
  for (int off = 32; off > 0; off >>= 1) {
#pragma unroll
    for (int r = 0; r < 8; ++r) {
      ar[r] += __shfl_xor(ar[r], off);
      ai[r] += __shfl_xor(ai[r], off);
    }
  }
  if (lane == 0) {
#pragma unroll
    for (int r = 0; r < 8; ++r) {
      red[wave][2 * r + 0] = ar[r];
      red[wave][2 * r + 1] = ai[r];
    }
  }
  __syncthreads();
  if (tid < 8) {
    const float Wr = red[0][2 * tid] + red[1][2 * tid] + red[2][2 * tid] + red[3][2 * tid];
    const float Wi = red[0][2 * tid + 1] + red[1][2 * tid + 1] +
                     red[2][2 * tid + 1] + red[3][2 * tid + 1];
    const int row = row0 + tid;
    const float omega = *omega_p;
    const float dt = *dt_p;
    const float inv2n = 1.0f / (2.0f * (float)NN);
    const float zr = z_old[2 * row];
    const float zi = z_old[2 * row + 1];
    const float z2r = zr * zr - zi * zi;
    const float z2i = 2.0f * zr * zi;
    const float t1r = -inv2n * (Wr * z2r + Wi * z2i);
    const float t1i = -inv2n * (Wr * z2i - Wi * z2r);
    float nr = zr + dt * (t1r + omega * zr + inv2n * Wr);
    float ni = zi + dt * (t1i + omega * zi + inv2n * Wi);
    const float a = sqrtf(nr * nr + ni * ni);
    if (a >= CLAMP_V) { nr = nr / a * CLAMP_V; ni = ni / a * CLAMP_V; }
    z_new[2 * row] = nr;
    z_new[2 * row + 1] = ni;
  }
}

__global__ __launch_bounds__(256) void finalize_kernel(const float* __restrict__ z,
                                                       float* __restrict__ out) {
  int i = blockIdx.x * blockDim.x + threadIdx.x;
  if (i < NN) {
    float x = z[2 * i], y = z[2 * i + 1];
    float n = sqrtf(x * x + y * y);
    if (n >= CLAMP_V) { x = x / n * CLAMP_V; y = y / n * CLAMP_V; }
    out[2 * i] = x;
    out[2 * i + 1] = y;
  }
}

extern "C" void kernel_launch(void* const* d_in, const int* in_sizes, int n_in,
                              void* d_out, int out_size, void* d_ws, size_t ws_size,
                              hipStream_t stream) {
  const float* z_in = (const float*)d_in[0];      // [8192,2] f32
  const float* K = (const float*)d_in[1];         // [8192,8192] f32
  const float* omega_p = (const float*)d_in[2];   // scalar f32
  const float* dt_p = (const float*)d_in[3];      // scalar f32
  float* out = (float*)d_out;

  char* ws = (char*)d_ws;
  const size_t kq_bytes = (size_t)NN * WPR * sizeof(unsigned);          // 32 MiB
  const size_t sc_bytes = (size_t)NN * sizeof(float);                   // 32 KiB
  const size_t tz_bytes = (size_t)(NN / 2) * sizeof(unsigned long long);// 32 KiB each
  const size_t need = kq_bytes + sc_bytes + 2 * tz_bytes + 256;
  const bool use_q = ws_size >= need;

  if (use_q) {
    size_t off = 0;
    unsigned* Kq = (unsigned*)(ws + off); off += kq_bytes;
    float* scales = (float*)(ws + off); off += sc_bytes;
    unsigned long long* tz0 = (unsigned long long*)(ws + off); off += tz_bytes;
    unsigned long long* tz1 = (unsigned long long*)(ws + off); off += tz_bytes;
    float* scz = (float*)(ws + off);

    quant4_kernel<<<NN, 256, 0, stream>>>(K, Kq, scales);
    prep_kernel<<<1, 256, 0, stream>>>(z_in, tz0, tz1, scz);
    persist_kernel<<<NBLK, TPB, 0, stream>>>(Kq, scales, z_in, tz0, tz1,
                                             scz, omega_p, dt_p, out);
  } else {
    float* zb0 = (float*)ws;
    float* zb1 = zb0 + NN * 2;
    const float* src = z_in;
    for (int s = 0; s < STEPS; ++s) {
      float* dst = (s & 1) ? zb1 : zb0;
      step_f32<<<NN / 8, 256, 0, stream>>>(K, src, dst, omega_p, dt_p);
      src = dst;
    }
    finalize_kernel<<<(NN + 255) / 256, 256, 0, stream>>>(src, out);
  }
}